// Round 12
// baseline (531.508 us; speedup 1.0000x reference)
//
#include <hip/hip_runtime.h>

// LSTM decoder: B=1024, S=256, H=128, O=7, T=512
// gates = h @ (W_ih+W_hh).T + (b_ih+b_hh); c'=sig(f)c+sig(i)tanh(g);
// h'=sig(o)tanh(c'); pred = h' @ W_out.T + b_out
//
// Round 12 = round 11 verbatim with __launch_bounds__(512, 2).
// Insight: every spilling round (2/3/6/9/10/11) asked for 4 waves/EU ->
// 128-reg COMPILER cap -> arch/AGPR split spill. Rounds 1/5/7/8 at (512,2)
// always allocated exactly 128 VGPR cleanly -- and 128 VGPR already
// permits 16 waves/CU = TWO 8-wave blocks in HARDWARE (m69). Their 23%
// occupancy was grid-limited (256 blocks = 1/CU), not register-limited.
// So: 512 blocks (RB=2) + natural 128-reg allocation -> 2 independent
// anti-phase blocks per CU, no allocator fight.

#define HH   128
#define SSEQ 256
#define TT   512
#define OO   7
#define RB   2
#define HSTR 144          // ring row stride in shorts (288B = 8-bank skew)
#define RING 32
#define SLOT (RB * HSTR)  // shorts per ring slot

typedef __attribute__((ext_vector_type(8))) short short8;
typedef __attribute__((ext_vector_type(4))) float f32x4;

__device__ __forceinline__ unsigned short f2bf(float x) {
    union { float f; unsigned u; } v; v.f = x;
    return (unsigned short)((v.u + 0x7FFF + ((v.u >> 16) & 1)) >> 16); // RNE
}
__device__ __forceinline__ float sigmoidf_(float x) {
    return __builtin_amdgcn_rcpf(1.f + __expf(-x));
}
__device__ __forceinline__ float tanhf_(float x) {
    return 1.f - 2.f * __builtin_amdgcn_rcpf(__expf(2.f * x) + 1.f);
}

__global__ void __launch_bounds__(512, 2)
lstm_decoder_kernel(const float* __restrict__ ctx,
                    const float* __restrict__ Wih,
                    const float* __restrict__ Whh,
                    const float* __restrict__ bih,
                    const float* __restrict__ bhh,
                    const float* __restrict__ Wout,
                    const float* __restrict__ bout,
                    float* __restrict__ out) {
    // h ring: slot t&31 holds h_t (bf16, RB rows padded to HSTR)
    __shared__ __align__(16) unsigned short h_ring[RING * SLOT];   // 18 KB
    // W_out B-fragments, lane-indexed (conflict-free): [kt][lane][8]
    __shared__ __align__(16) unsigned short wo_frag[4][64][8];     // 4 KB
    // folded gate biases per h-column: [col][i,f,g,o]
    __shared__ __align__(16) float bias_lds[HH][4];                // 2 KB
    __shared__ float bout_lds[16];

    const int tid  = threadIdx.x;
    const int lane = tid & 63;
    const int wave = tid >> 6;
    const int rowBase = blockIdx.x * RB;

    const int lo  = lane & 15;
    const int hi  = lane >> 4;       // 0..3
    const int col = wave * 16 + lo;  // this lane's gate/h column (0..127)
    const int arw = lo & 1;          // A-tile real row (2 rows replicated to 16)
    const int erow = hi & 1;         // elementwise row (dup across hi pairs)

    // W fragments (B-operand): wave w, gate g -> n = g*128 + w*16 + lo,
    // lane holds W[n][k0..k0+7], k0 = kt*32 + hi*8
    short8 wfrag[4][4];
#pragma unroll
    for (int g = 0; g < 4; ++g) {
        const int n = g * HH + wave * 16 + lo;
#pragma unroll
        for (int kt = 0; kt < 4; ++kt) {
            const int k0 = kt * 32 + hi * 8;
            const float* p1 = Wih + (size_t)n * HH + k0;
            const float* p2 = Whh + (size_t)n * HH + k0;
            short8 w;
#pragma unroll
            for (int j = 0; j < 8; ++j) w[j] = (short)f2bf(p1[j] + p2[j]);
            wfrag[g][kt] = w;
        }
    }

    // folded biases -> LDS (threads 0..127, one column each)
    if (tid < HH) {
#pragma unroll
        for (int g = 0; g < 4; ++g)
            bias_lds[tid][g] = bih[g * HH + tid] + bhh[g * HH + tid];
    }
    if (tid < 16) bout_lds[tid] = (tid < OO) ? bout[tid] : 0.f;

    // W_out B-fragments into LDS (wave 1 to spread setup work)
    if (wave == 1) {
#pragma unroll
        for (int kt = 0; kt < 4; ++kt) {
            const int k0 = kt * 32 + hi * 8;
            short8 w;
#pragma unroll
            for (int j = 0; j < 8; ++j)
                w[j] = (lo < OO) ? (short)f2bf(Wout[(size_t)lo * HH + k0 + j]) : (short)0;
            *(short8*)&wo_frag[kt][lane][0] = w;
        }
    }

    // h0 = context_seq[:, S-1, :] -> ring slot 0
    if (hi < RB) {
        const float v = ctx[(size_t)(rowBase + hi) * SSEQ * HH + (size_t)(SSEQ - 1) * HH + col];
        h_ring[hi * HSTR + col] = f2bf(v);
    }
    float c_st = 0.f;   // cell state for (row erow, col); dup across hi pairs
    __syncthreads();

    for (int it = 0; it <= TT; ++it) {
        // ---- batched pred phase every 32 steps: preds for s = it-32..it-1.
        // Ring: slot 0 = h_it (s=it-1), slot q>=1 = h_{it-32+q} (s=it-33+q).
        // 64 pred rows (32 slots x 2 batch rows) = 4 full-M tiles, waves 0..3.
        if (it >= 32 && (it & 31) == 0) {
            if (wave < 4) {
                // A row (within tile) = lo -> rho = 16*wave + lo
                const int abase = (8 * wave + (lo >> 1)) * SLOT + (lo & 1) * HSTR + hi * 8;
                const float bp = bout_lds[lo];
                f32x4 accp = {bp, bp, bp, bp};
#pragma unroll
                for (int kt = 0; kt < 4; ++kt) {
                    const short8 a  = *(const short8*)&h_ring[abase + kt * 32];
                    const short8 wp = *(const short8*)&wo_frag[kt][lane][0];
                    accp = __builtin_amdgcn_mfma_f32_16x16x32_bf16(a, wp, accp, 0, 0, 0);
                }
                // C: col=lo (output col), row=4*hi+r -> rho=16*wave+4*hi+r
                if (lo < OO) {
#pragma unroll
                    for (int r = 0; r < 4; ++r) {
                        const int q  = 8 * wave + 2 * hi + (r >> 1);  // rho>>1
                        const int br = r & 1;
                        const int s  = q ? (it - 33 + q) : (it - 1);
                        out[(size_t)(rowBase + br) * TT * OO + (size_t)s * OO + lo] = accp[r];
                    }
                }
            }
            __syncthreads();   // pred reads done before slots get overwritten
        }

        if (it == TT) break;

        // ---- LSTM step: h_it (slot it&31) -> h_{it+1} ----
        // JIT A-fragments: one short8 live + one prefetch (8 regs, was 16)
        const int abase = (it & 31) * SLOT + arw * HSTR + hi * 8;
        short8 a_cur = *(const short8*)&h_ring[abase];
        f32x4 acc0 = {0.f, 0.f, 0.f, 0.f};
        f32x4 acc1 = {0.f, 0.f, 0.f, 0.f};
        f32x4 acc2 = {0.f, 0.f, 0.f, 0.f};
        f32x4 acc3 = {0.f, 0.f, 0.f, 0.f};
#pragma unroll
        for (int kt = 0; kt < 4; ++kt) {
            short8 a_nxt;
            if (kt < 3) a_nxt = *(const short8*)&h_ring[abase + (kt + 1) * 32];
            acc0 = __builtin_amdgcn_mfma_f32_16x16x32_bf16(a_cur, wfrag[0][kt], acc0, 0, 0, 0);
            acc1 = __builtin_amdgcn_mfma_f32_16x16x32_bf16(a_cur, wfrag[1][kt], acc1, 0, 0, 0);
            acc2 = __builtin_amdgcn_mfma_f32_16x16x32_bf16(a_cur, wfrag[2][kt], acc2, 0, 0, 0);
            acc3 = __builtin_amdgcn_mfma_f32_16x16x32_bf16(a_cur, wfrag[3][kt], acc3, 0, 0, 0);
            if (kt < 3) a_cur = a_nxt;
        }

        // C row = 4*hi + reg; A row m holds real row m&1 -> reg r at ANY hi is
        // the gate for real row r (r<RB). Select reg r = erow in-register.
        const float gi = erow ? acc0[1] : acc0[0];
        const float gf = erow ? acc1[1] : acc1[0];
        const float gg = erow ? acc2[1] : acc2[0];
        const float go = erow ? acc3[1] : acc3[0];

        const f32x4 b4 = *(const f32x4*)&bias_lds[col][0];
        const float si_ = sigmoidf_(gi + b4[0]);
        const float sf_ = sigmoidf_(gf + b4[1]);
        const float tg  = tanhf_(gg + b4[2]);
        const float so_ = sigmoidf_(go + b4[3]);
        c_st = __builtin_fmaf(sf_, c_st, si_ * tg);
        const float hnew = so_ * tanhf_(c_st);

        if (hi < RB)
            h_ring[((it + 1) & 31) * SLOT + hi * HSTR + col] = f2bf(hnew);
        __syncthreads();
    }
}

extern "C" void kernel_launch(void* const* d_in, const int* in_sizes, int n_in,
                              void* d_out, int out_size, void* d_ws, size_t ws_size,
                              hipStream_t stream) {
    const float* ctx  = (const float*)d_in[0];
    const float* Wih  = (const float*)d_in[1];
    const float* Whh  = (const float*)d_in[2];
    const float* bih  = (const float*)d_in[3];
    const float* bhh  = (const float*)d_in[4];
    const float* Wout = (const float*)d_in[5];
    const float* bout = (const float*)d_in[6];
    float* out = (float*)d_out;

    lstm_decoder_kernel<<<dim3(1024 / RB), dim3(512), 0, stream>>>(
        ctx, Wih, Whh, bih, bhh, Wout, bout, out);
}

// Round 13
// 325.728 us; speedup vs baseline: 1.6318x; 1.6318x over previous
//
#include <hip/hip_runtime.h>

// LSTM decoder: B=1024, S=256, H=128, O=7, T=512
// gates = h @ (W_ih+W_hh).T + (b_ih+b_hh); c'=sig(f)c+sig(i)tanh(g);
// h'=sig(o)tanh(c'); pred = h' @ W_out.T + b_out
//
// Round 13 = round 8 (325us-class: 256 blocks x 512 thr, RB=4, 32-slot ring,
// batched pred every 32 steps, 0 bank conflicts, VGPR=128 clean at (512,2))
// + step-body overlap compression:
//  - MFMA gate pairs (i,g) then (f,o); sigmoid(i)/tanh(g)/p=si*tg issue in
//    the shadow of the (f,o) MFMAs (separate VALU/trans vs MFMA pipes)
//  - biases folded into MFMA C-init (splat), post-adds removed
//  - 4 upfront A-frag ds_reads (independent, pipelined latency)
// 2-blocks/CU axis closed: rounds 2/3/6/9/10/11 spill, round 12 proves the
// unified-file footprint (128 arch + AGPR) caps HW at 8 waves/CU.

#define HH   128
#define SSEQ 256
#define TT   512
#define OO   7
#define RB   4
#define HSTR 144          // ring row stride in shorts (288B = 8-bank skew)
#define RING 32
#define SLOT (RB * HSTR)  // shorts per ring slot

typedef __attribute__((ext_vector_type(8))) short short8;
typedef __attribute__((ext_vector_type(4))) float f32x4;

__device__ __forceinline__ unsigned short f2bf(float x) {
    union { float f; unsigned u; } v; v.f = x;
    return (unsigned short)((v.u + 0x7FFF + ((v.u >> 16) & 1)) >> 16); // RNE
}
__device__ __forceinline__ float sigmoidf_(float x) {
    return __builtin_amdgcn_rcpf(1.f + __expf(-x));
}
__device__ __forceinline__ float tanhf_(float x) {
    return 1.f - 2.f * __builtin_amdgcn_rcpf(__expf(2.f * x) + 1.f);
}

__global__ void __launch_bounds__(512, 2)
lstm_decoder_kernel(const float* __restrict__ ctx,
                    const float* __restrict__ Wih,
                    const float* __restrict__ Whh,
                    const float* __restrict__ bih,
                    const float* __restrict__ bhh,
                    const float* __restrict__ Wout,
                    const float* __restrict__ bout,
                    float* __restrict__ out) {
    // h ring: slot t&31 holds h_t (bf16), rows padded to HSTR
    __shared__ __align__(16) unsigned short h_ring[RING * SLOT];   // 36 KB
    // W_out B-fragments, lane-indexed (conflict-free): [kt][lane][8]
    __shared__ __align__(16) unsigned short wo_frag[4][64][8];     // 4 KB

    const int tid  = threadIdx.x;
    const int lane = tid & 63;
    const int wave = tid >> 6;
    const int rowBase = blockIdx.x * RB;

    const int lo  = lane & 15;
    const int hi  = lane >> 4;       // 0..3: this lane's batch row AND k-slice
    const int col = wave * 16 + lo;  // this lane's gate/h column (0..127)
    const int arw = lo & 3;          // A-tile real row (rows replicated to 16)

    // folded biases for this lane's column (go into MFMA C-init)
    const float bi  = bih[col]          + bhh[col];
    const float bf_ = bih[HH + col]     + bhh[HH + col];
    const float bg  = bih[2 * HH + col] + bhh[2 * HH + col];
    const float bo  = bih[3 * HH + col] + bhh[3 * HH + col];
    const float bo_pred = (lo < OO) ? bout[lo] : 0.f;

    // W fragments (B-operand): wave w, gate g -> n = g*128 + w*16 + lo,
    // lane holds W[n][k0..k0+7], k0 = kt*32 + hi*8
    short8 wfrag[4][4];
#pragma unroll
    for (int g = 0; g < 4; ++g) {
        const int n = g * HH + wave * 16 + lo;
#pragma unroll
        for (int kt = 0; kt < 4; ++kt) {
            const int k0 = kt * 32 + hi * 8;
            const float* p1 = Wih + (size_t)n * HH + k0;
            const float* p2 = Whh + (size_t)n * HH + k0;
            short8 w;
#pragma unroll
            for (int j = 0; j < 8; ++j) w[j] = (short)f2bf(p1[j] + p2[j]);
            wfrag[g][kt] = w;
        }
    }

    // W_out B-fragments into LDS (wave 0): lane holds Wout[lo][kt*32+hi*8..+8]
    if (wave == 0) {
#pragma unroll
        for (int kt = 0; kt < 4; ++kt) {
            const int k0 = kt * 32 + hi * 8;
            short8 w;
#pragma unroll
            for (int j = 0; j < 8; ++j)
                w[j] = (lo < OO) ? (short)f2bf(Wout[(size_t)lo * HH + k0 + j]) : (short)0;
            *(short8*)&wo_frag[kt][lane][0] = w;
        }
    }

    // h0 = context_seq[:, S-1, :] -> ring slot 0
    {
        const float v = ctx[(size_t)(rowBase + hi) * SSEQ * HH + (size_t)(SSEQ - 1) * HH + col];
        h_ring[hi * HSTR + col] = f2bf(v);
    }
    float c_st = 0.f;   // cell state for (row hi, col)
    __syncthreads();

    for (int it = 0; it <= TT; ++it) {
        // ---- batched pred phase: every 32 steps, preds for s = it-32..it-1.
        // Ring holds h_{it-31}..h_{it}; pred[s] = h_{s+1} @ Wout.T + b.
        if (it >= 32 && (it & 31) == 0) {
            f32x4 accp = {bo_pred, bo_pred, bo_pred, bo_pred};
            const int abase = (4 * wave + (lo >> 2)) * SLOT + (lo & 3) * HSTR + hi * 8;
#pragma unroll
            for (int kt = 0; kt < 4; ++kt) {
                const short8 a  = *(const short8*)&h_ring[abase + kt * 32];
                const short8 wp = *(const short8*)&wo_frag[kt][lane][0];
                accp = __builtin_amdgcn_mfma_f32_16x16x32_bf16(a, wp, accp, 0, 0, 0);
            }
            // C: col=lo, row(within tile)=4*hi+r -> slot sig=4*wave+hi, batch row r
            if (lo < OO) {
                const int sig = 4 * wave + hi;
                const int s   = sig ? (it - 33 + sig) : (it - 1);
#pragma unroll
                for (int r = 0; r < 4; ++r)
                    out[(size_t)(rowBase + r) * TT * OO + (size_t)s * OO + lo] = accp[r];
            }
            __syncthreads();   // pred reads done before slots get overwritten
        }

        if (it == TT) break;

        // ---- LSTM step: h_it (slot it&31) -> h_{it+1} (slot (it+1)&31) ----
        const int abase = (it & 31) * SLOT + arw * HSTR + hi * 8;
        short8 afrag[4];
#pragma unroll
        for (int kt = 0; kt < 4; ++kt)
            afrag[kt] = *(const short8*)&h_ring[abase + kt * 32];

        const bool m1 = (hi == 1), m2 = (hi == 2), m3 = (hi == 3);

        // pair 1: gates i and g (biases in C-init)
        f32x4 accI = {bi, bi, bi, bi};
        f32x4 accG = {bg, bg, bg, bg};
#pragma unroll
        for (int kt = 0; kt < 4; ++kt) {
            accI = __builtin_amdgcn_mfma_f32_16x16x32_bf16(afrag[kt], wfrag[0][kt], accI, 0, 0, 0);
            accG = __builtin_amdgcn_mfma_f32_16x16x32_bf16(afrag[kt], wfrag[2][kt], accG, 0, 0, 0);
        }
        // early eltwise for i,g — issues in the shadow of pair-2 MFMAs
        const float gi = m3 ? accI[3] : m2 ? accI[2] : m1 ? accI[1] : accI[0];
        const float gg = m3 ? accG[3] : m2 ? accG[2] : m1 ? accG[1] : accG[0];
        const float si_ = sigmoidf_(gi);
        const float tg  = tanhf_(gg);
        const float p   = si_ * tg;

        // pair 2: gates f and o
        f32x4 accF = {bf_, bf_, bf_, bf_};
        f32x4 accO = {bo, bo, bo, bo};
#pragma unroll
        for (int kt = 0; kt < 4; ++kt) {
            accF = __builtin_amdgcn_mfma_f32_16x16x32_bf16(afrag[kt], wfrag[1][kt], accF, 0, 0, 0);
            accO = __builtin_amdgcn_mfma_f32_16x16x32_bf16(afrag[kt], wfrag[3][kt], accO, 0, 0, 0);
        }
        const float gf = m3 ? accF[3] : m2 ? accF[2] : m1 ? accF[1] : accF[0];
        const float go = m3 ? accO[3] : m2 ? accO[2] : m1 ? accO[1] : accO[0];

        const float sf_ = sigmoidf_(gf);
        c_st = __builtin_fmaf(sf_, c_st, p);
        const float so_ = sigmoidf_(go);
        const float hnew = so_ * tanhf_(c_st);

        h_ring[((it + 1) & 31) * SLOT + hi * HSTR + col] = f2bf(hnew);
        __syncthreads();
    }
}

extern "C" void kernel_launch(void* const* d_in, const int* in_sizes, int n_in,
                              void* d_out, int out_size, void* d_ws, size_t ws_size,
                              hipStream_t stream) {
    const float* ctx  = (const float*)d_in[0];
    const float* Wih  = (const float*)d_in[1];
    const float* Whh  = (const float*)d_in[2];
    const float* bih  = (const float*)d_in[3];
    const float* bhh  = (const float*)d_in[4];
    const float* Wout = (const float*)d_in[5];
    const float* bout = (const float*)d_in[6];
    float* out = (float*)d_out;

    lstm_decoder_kernel<<<dim3(1024 / RB), dim3(512), 0, stream>>>(
        ctx, Wih, Whh, bih, bhh, Wout, bout, out);
}

// Round 14
// 314.037 us; speedup vs baseline: 1.6925x; 1.0372x over previous
//
#include <hip/hip_runtime.h>

// LSTM decoder: B=1024, S=256, H=128, O=7, T=512
// gates = h @ (W_ih+W_hh).T + (b_ih+b_hh); c'=sig(f)c+sig(i)tanh(g);
// h'=sig(o)tanh(c'); pred = h' @ W_out.T + b_out
//
// Round 14 = round 8/13 base (256 blocks x 512 thr, RB=4, 32-slot ring,
// batched pred, 0 conflicts, VGPR=128 clean) + FORCED MFMA/VALU interleave:
// gate chains I,G,F,O with each gate's select+trans chunk wedged between
// MFMA clusters, pinned with __builtin_amdgcn_sched_barrier(0). Round 13
// failed because the scheduler re-clustered the independent MFMAs around
// the eltwise; the sched_barriers forbid that, so each wave's VALU chunks
// issue while the OTHER wave's MFMA cluster occupies the matrix pipe
// (phase-serialization 620+480 -> overlapped ~620+tail).

#define HH   128
#define SSEQ 256
#define TT   512
#define OO   7
#define RB   4
#define HSTR 144          // ring row stride in shorts (288B = 8-bank skew)
#define RING 32
#define SLOT (RB * HSTR)  // shorts per ring slot

typedef __attribute__((ext_vector_type(8))) short short8;
typedef __attribute__((ext_vector_type(4))) float f32x4;

#define SB() __builtin_amdgcn_sched_barrier(0)

__device__ __forceinline__ unsigned short f2bf(float x) {
    union { float f; unsigned u; } v; v.f = x;
    return (unsigned short)((v.u + 0x7FFF + ((v.u >> 16) & 1)) >> 16); // RNE
}
__device__ __forceinline__ float sigmoidf_(float x) {
    return __builtin_amdgcn_rcpf(1.f + __expf(-x));
}
__device__ __forceinline__ float tanhf_(float x) {
    return 1.f - 2.f * __builtin_amdgcn_rcpf(__expf(2.f * x) + 1.f);
}

__global__ void __launch_bounds__(512, 2)
lstm_decoder_kernel(const float* __restrict__ ctx,
                    const float* __restrict__ Wih,
                    const float* __restrict__ Whh,
                    const float* __restrict__ bih,
                    const float* __restrict__ bhh,
                    const float* __restrict__ Wout,
                    const float* __restrict__ bout,
                    float* __restrict__ out) {
    // h ring: slot t&31 holds h_t (bf16), rows padded to HSTR
    __shared__ __align__(16) unsigned short h_ring[RING * SLOT];   // 36 KB
    // W_out B-fragments, lane-indexed (conflict-free): [kt][lane][8]
    __shared__ __align__(16) unsigned short wo_frag[4][64][8];     // 4 KB

    const int tid  = threadIdx.x;
    const int lane = tid & 63;
    const int wave = tid >> 6;
    const int rowBase = blockIdx.x * RB;

    const int lo  = lane & 15;
    const int hi  = lane >> 4;       // 0..3: this lane's batch row AND k-slice
    const int col = wave * 16 + lo;  // this lane's gate/h column (0..127)
    const int arw = lo & 3;          // A-tile real row (rows replicated to 16)

    // folded biases for this lane's column (go into MFMA C-init)
    const float bi  = bih[col]          + bhh[col];
    const float bf_ = bih[HH + col]     + bhh[HH + col];
    const float bg  = bih[2 * HH + col] + bhh[2 * HH + col];
    const float bo  = bih[3 * HH + col] + bhh[3 * HH + col];
    const float bo_pred = (lo < OO) ? bout[lo] : 0.f;

    // W fragments (B-operand): wave w, gate g -> n = g*128 + w*16 + lo,
    // lane holds W[n][k0..k0+7], k0 = kt*32 + hi*8
    short8 wfrag[4][4];
#pragma unroll
    for (int g = 0; g < 4; ++g) {
        const int n = g * HH + wave * 16 + lo;
#pragma unroll
        for (int kt = 0; kt < 4; ++kt) {
            const int k0 = kt * 32 + hi * 8;
            const float* p1 = Wih + (size_t)n * HH + k0;
            const float* p2 = Whh + (size_t)n * HH + k0;
            short8 w;
#pragma unroll
            for (int j = 0; j < 8; ++j) w[j] = (short)f2bf(p1[j] + p2[j]);
            wfrag[g][kt] = w;
        }
    }

    // W_out B-fragments into LDS (wave 0): lane holds Wout[lo][kt*32+hi*8..+8]
    if (wave == 0) {
#pragma unroll
        for (int kt = 0; kt < 4; ++kt) {
            const int k0 = kt * 32 + hi * 8;
            short8 w;
#pragma unroll
            for (int j = 0; j < 8; ++j)
                w[j] = (lo < OO) ? (short)f2bf(Wout[(size_t)lo * HH + k0 + j]) : (short)0;
            *(short8*)&wo_frag[kt][lane][0] = w;
        }
    }

    // h0 = context_seq[:, S-1, :] -> ring slot 0
    {
        const float v = ctx[(size_t)(rowBase + hi) * SSEQ * HH + (size_t)(SSEQ - 1) * HH + col];
        h_ring[hi * HSTR + col] = f2bf(v);
    }
    float c_st = 0.f;   // cell state for (row hi, col)
    __syncthreads();

    for (int it = 0; it <= TT; ++it) {
        // ---- batched pred phase: every 32 steps, preds for s = it-32..it-1.
        if (it >= 32 && (it & 31) == 0) {
            f32x4 accp = {bo_pred, bo_pred, bo_pred, bo_pred};
            const int pbase = (4 * wave + (lo >> 2)) * SLOT + (lo & 3) * HSTR + hi * 8;
#pragma unroll
            for (int kt = 0; kt < 4; ++kt) {
                const short8 a  = *(const short8*)&h_ring[pbase + kt * 32];
                const short8 wp = *(const short8*)&wo_frag[kt][lane][0];
                accp = __builtin_amdgcn_mfma_f32_16x16x32_bf16(a, wp, accp, 0, 0, 0);
            }
            if (lo < OO) {
                const int sig = 4 * wave + hi;
                const int s   = sig ? (it - 33 + sig) : (it - 1);
#pragma unroll
                for (int r = 0; r < 4; ++r)
                    out[(size_t)(rowBase + r) * TT * OO + (size_t)s * OO + lo] = accp[r];
            }
            __syncthreads();   // pred reads done before slots get overwritten
        }

        if (it == TT) break;

        // ---- LSTM step: h_it (slot it&31) -> h_{it+1} (slot (it+1)&31) ----
        const int abase = (it & 31) * SLOT + arw * HSTR + hi * 8;
        short8 afrag[4];
#pragma unroll
        for (int kt = 0; kt < 4; ++kt)
            afrag[kt] = *(const short8*)&h_ring[abase + kt * 32];

        const bool m1 = (hi == 1), m2 = (hi == 2), m3 = (hi == 3);

        f32x4 accI = {bi, bi, bi, bi};
        f32x4 accG = {bg, bg, bg, bg};
        f32x4 accF = {bf_, bf_, bf_, bf_};
        f32x4 accO = {bo, bo, bo, bo};

        // --- cluster I ---
#pragma unroll
        for (int kt = 0; kt < 4; ++kt)
            accI = __builtin_amdgcn_mfma_f32_16x16x32_bf16(afrag[kt], wfrag[0][kt], accI, 0, 0, 0);
        SB();
        // --- cluster G (covers accI latency) ---
#pragma unroll
        for (int kt = 0; kt < 4; ++kt)
            accG = __builtin_amdgcn_mfma_f32_16x16x32_bf16(afrag[kt], wfrag[2][kt], accG, 0, 0, 0);
        SB();
        // VALU chunk 1: sigmoid(i)
        const float gi  = m3 ? accI[3] : m2 ? accI[2] : m1 ? accI[1] : accI[0];
        const float si_ = sigmoidf_(gi);
        SB();
        // --- cluster F ---
#pragma unroll
        for (int kt = 0; kt < 4; ++kt)
            accF = __builtin_amdgcn_mfma_f32_16x16x32_bf16(afrag[kt], wfrag[1][kt], accF, 0, 0, 0);
        SB();
        // VALU chunk 2: tanh(g), p = si*tg
        const float gg = m3 ? accG[3] : m2 ? accG[2] : m1 ? accG[1] : accG[0];
        const float tg = tanhf_(gg);
        const float p  = si_ * tg;
        SB();
        // --- cluster O ---
#pragma unroll
        for (int kt = 0; kt < 4; ++kt)
            accO = __builtin_amdgcn_mfma_f32_16x16x32_bf16(afrag[kt], wfrag[3][kt], accO, 0, 0, 0);
        SB();
        // VALU chunk 3: sigmoid(f), c update, tanh(c)
        const float gf  = m3 ? accF[3] : m2 ? accF[2] : m1 ? accF[1] : accF[0];
        const float sf_ = sigmoidf_(gf);
        c_st = __builtin_fmaf(sf_, c_st, p);
        const float tc  = tanhf_(c_st);
        SB();
        // VALU chunk 4: sigmoid(o), h, write
        const float go  = m3 ? accO[3] : m2 ? accO[2] : m1 ? accO[1] : accO[0];
        const float so_ = sigmoidf_(go);
        const float hnew = so_ * tc;

        h_ring[((it + 1) & 31) * SLOT + hi * HSTR + col] = f2bf(hnew);
        __syncthreads();
    }
}

extern "C" void kernel_launch(void* const* d_in, const int* in_sizes, int n_in,
                              void* d_out, int out_size, void* d_ws, size_t ws_size,
                              hipStream_t stream) {
    const float* ctx  = (const float*)d_in[0];
    const float* Wih  = (const float*)d_in[1];
    const float* Whh  = (const float*)d_in[2];
    const float* bih  = (const float*)d_in[3];
    const float* bhh  = (const float*)d_in[4];
    const float* Wout = (const float*)d_in[5];
    const float* bout = (const float*)d_in[6];
    float* out = (float*)d_out;

    lstm_decoder_kernel<<<dim3(1024 / RB), dim3(512), 0, stream>>>(
        ctx, Wih, Whh, bih, bhh, Wout, bout, out);
}